// Round 7
// baseline (334.740 us; speedup 1.0000x reference)
//
#include <hip/hip_runtime.h>
#include <math.h>

#define EPSF 1e-5f

typedef short bf16x8 __attribute__((ext_vector_type(8)));
typedef float f32x4 __attribute__((ext_vector_type(4)));

static __device__ __forceinline__ unsigned short f2bf(float x) {
  unsigned u = __float_as_uint(x);
  unsigned r = (u + 0x7FFFu + ((u >> 16) & 1u)) >> 16;
  return (unsigned short)r;
}

union BU { uint4 u; bf16x8 v; };

// ---------------- Prep: pack [Wf|Ws] permuted rows into MFMA B-fragment order.
// Row space k=0..159: k<32 -> W[128+k] (eattr rows); k>=32 -> W[k-32]
// (x_dst rows 0..63 then x_src rows 64..127). Frag: lane l holds
// B[k=(l>>4)*8+i][col=(t8&3)*16+(l&15)], t8<4 => Wf, else Ws.
__global__ __launch_bounds__(512) void bpack_kernel(
    const float* __restrict__ Wf, const float* __restrict__ Ws,
    unsigned short* __restrict__ Bfrag) {
  const int ks = blockIdx.x;  // 0..4
  const int t8 = threadIdx.x >> 6, l = threadIdx.x & 63;
  const int q = l & 15, g = l >> 4;
  const float* W = (t8 < 4) ? Wf : Ws;
  const int col = (t8 & 3) * 16 + q;
  unsigned short out[8];
#pragma unroll
  for (int i = 0; i < 8; ++i) {
    int r = ks * 32 + g * 8 + i;
    int wr = (r < 32) ? (128 + r) : (r - 32);
    out[i] = f2bf(W[(size_t)wr * 64 + col]);
  }
  *(uint4*)&Bfrag[((size_t)(ks * 8 + t8) * 64 + l) * 8] = *(uint4*)out;
}

// ---------------- CSR build: histogram of dst ----------------
__global__ void hist_kernel(const int* __restrict__ ei, int* __restrict__ deg,
                            int E) {
  int i = blockIdx.x * blockDim.x + threadIdx.x;
  if (i < E) atomicAdd(&deg[ei[E + i]], 1);
}

// ---------------- CSR build: 3-phase parallel exclusive scan ----------------
__global__ __launch_bounds__(256) void scan_a(const int* __restrict__ deg,
                                              int* __restrict__ bsum, int N) {
  const int idx = blockIdx.x * 256 + threadIdx.x;
  int v = (idx < N) ? deg[idx] : 0;
#pragma unroll
  for (int o = 32; o > 0; o >>= 1) v += __shfl_down(v, o);
  __shared__ int ws4[4];
  if ((threadIdx.x & 63) == 0) ws4[threadIdx.x >> 6] = v;
  __syncthreads();
  if (threadIdx.x == 0) bsum[blockIdx.x] = ws4[0] + ws4[1] + ws4[2] + ws4[3];
}

__global__ __launch_bounds__(256) void scan_b(const int* __restrict__ bsum,
                                              int* __restrict__ bpre, int NB) {
  const int t = threadIdx.x;
  const int lane = t & 63, w = t >> 6;
  int v = (t < NB) ? bsum[t] : 0;
  int sc = v;
#pragma unroll
  for (int o = 1; o < 64; o <<= 1) {
    int u = __shfl_up(sc, o);
    if (lane >= o) sc += u;
  }
  __shared__ int wsum[4];
  if (lane == 63) wsum[w] = sc;
  __syncthreads();
  int add = 0;
#pragma unroll
  for (int k = 0; k < 4; ++k) add += (k < w) ? wsum[k] : 0;
  bpre[t] = (sc - v) + add;
}

__global__ __launch_bounds__(256) void scan_c(const int* __restrict__ deg,
                                              const int* __restrict__ bpre,
                                              int* __restrict__ offsets,
                                              int* __restrict__ cursor, int N) {
  const int t = threadIdx.x;
  const int lane = t & 63, w = t >> 6;
  const int idx = blockIdx.x * 256 + t;
  int d = (idx < N) ? deg[idx] : 0;
  int sc = d;
#pragma unroll
  for (int o = 1; o < 64; o <<= 1) {
    int u = __shfl_up(sc, o);
    if (lane >= o) sc += u;
  }
  __shared__ int wsum[4];
  if (lane == 63) wsum[w] = sc;
  __syncthreads();
  int add = bpre[blockIdx.x];
#pragma unroll
  for (int k = 0; k < 4; ++k) add += (k < w) ? wsum[k] : 0;
  const int off = add + (sc - d);
  if (idx < N) {
    offsets[idx] = off;
    cursor[idx] = off;
    if (idx == N - 1) offsets[N] = off + d;
  }
}

// ---------------- CSR build: scatter (eattr_idx, src, dst) -----------------
__global__ void scatter_kernel(const int* __restrict__ ei,
                               int* __restrict__ cursor,
                               int4* __restrict__ epair4, int E) {
  int i = blockIdx.x * blockDim.x + threadIdx.x;
  if (i < E) {
    int dst = ei[E + i];
    int pos = atomicAdd(&cursor[dst], 1);
    epair4[pos] = make_int4(i, ei[i], dst, 0);
  }
}

// ---------------- K2: fused edge kernel. One block = 64-edge tile ------------
// A(64x160 bf16) = [eattr | x_dst | x_src] staged in LDS; B(160x128) in VGPRs
// (wave w owns N-tiles {w, w+4} = feats w*16..w*16+15 of lin_f and lin_s).
// 40 MFMA 16x16x32/wave, epilogue: +bias, sigmoid*softplus, per-lane
// run-compressed atomicAdd into agg (16-lane coalesced 64B chunks).
__global__ __launch_bounds__(256) void edge_fused(
    const int4* __restrict__ epair4, const float* __restrict__ eattr,
    const float* __restrict__ x, const unsigned short* __restrict__ Bfrag,
    const float* __restrict__ bfv_, const float* __restrict__ bsv_,
    float* __restrict__ agg, int E, int N) {
  __shared__ __align__(16) unsigned short Ash[5][64][40];  // 25.6 KB
  __shared__ __align__(16) int srcl[64];
  __shared__ __align__(16) int dstl[64];
  __shared__ __align__(16) int eidx[64];
  __shared__ __align__(4) unsigned char ridb[64];

  const int t = threadIdx.x, lane = t & 63, w = t >> 6;
  const int q = lane & 15, g = lane >> 4;
  const int base = blockIdx.x * 64;

  // B fragments: 10 x 16B loads per lane, wave-uniform tile ids
  bf16x8 Bf[5], Bs[5];
#pragma unroll
  for (int ks = 0; ks < 5; ++ks) {
    BU u1, u2;
    u1.u = ((const uint4*)Bfrag)[(size_t)((ks * 8 + w) * 64 + lane)];
    u2.u = ((const uint4*)Bfrag)[(size_t)((ks * 8 + w + 4) * 64 + lane)];
    Bf[ks] = u1.v;
    Bs[ks] = u2.v;
  }
  const int feat = w * 16 + q;
  const float bfv = bfv_[feat];
  const float bsv = bsv_[feat];

  // wave 0: edge meta + dst run-id scan (dst-sorted CSR order)
  if (w == 0) {
    const int eg = base + lane;
    int4 p = make_int4(0, 0, 0x7FFFFFFF, 0);
    if (eg < E) p = epair4[eg];
    eidx[lane] = p.x;
    srcl[lane] = p.y;
    dstl[lane] = p.z;
    int d = p.z;
    int dprev = __shfl_up(d, 1);
    int flag = (lane == 0 || d != dprev) ? 1 : 0;
    int sc = flag;
#pragma unroll
    for (int o = 1; o < 64; o <<= 1) {
      int u = __shfl_up(sc, o);
      if (lane >= o) sc += u;
    }
    ridb[lane] = (unsigned char)(sc - 1);
  }
  __syncthreads();

  // stage A tile: 4 threads per row; c covers eattr[8f] + x_dst[16f] + x_src[16f]
  {
    const int row = t >> 2, c = t & 3;
    const int ei_ = eidx[row];
    int d_ = dstl[row];
    if (d_ >= N) d_ = 0;  // tail sentinel clamp (staging only)
    const int s_ = srcl[row];

    const float* er = eattr + (size_t)ei_ * 32 + c * 8;
    float4 v0 = *(const float4*)er;
    float4 v1 = *(const float4*)(er + 4);
    bf16x8 sv;
    sv[0] = (short)f2bf(v0.x); sv[1] = (short)f2bf(v0.y);
    sv[2] = (short)f2bf(v0.z); sv[3] = (short)f2bf(v0.w);
    sv[4] = (short)f2bf(v1.x); sv[5] = (short)f2bf(v1.y);
    sv[6] = (short)f2bf(v1.z); sv[7] = (short)f2bf(v1.w);
    *(bf16x8*)&Ash[0][row][c * 8] = sv;

    const float* xd = x + (size_t)d_ * 64 + c * 16;
    float4 a0 = *(const float4*)xd;
    float4 a1 = *(const float4*)(xd + 4);
    float4 a2 = *(const float4*)(xd + 8);
    float4 a3 = *(const float4*)(xd + 12);
    bf16x8 s0, s1;
    s0[0] = (short)f2bf(a0.x); s0[1] = (short)f2bf(a0.y);
    s0[2] = (short)f2bf(a0.z); s0[3] = (short)f2bf(a0.w);
    s0[4] = (short)f2bf(a1.x); s0[5] = (short)f2bf(a1.y);
    s0[6] = (short)f2bf(a1.z); s0[7] = (short)f2bf(a1.w);
    s1[0] = (short)f2bf(a2.x); s1[1] = (short)f2bf(a2.y);
    s1[2] = (short)f2bf(a2.z); s1[3] = (short)f2bf(a2.w);
    s1[4] = (short)f2bf(a3.x); s1[5] = (short)f2bf(a3.y);
    s1[6] = (short)f2bf(a3.z); s1[7] = (short)f2bf(a3.w);
    *(bf16x8*)&Ash[1 + (c >> 1)][row][(c & 1) * 16] = s0;
    *(bf16x8*)&Ash[1 + (c >> 1)][row][(c & 1) * 16 + 8] = s1;

    const float* xs = x + (size_t)s_ * 64 + c * 16;
    float4 b0 = *(const float4*)xs;
    float4 b1 = *(const float4*)(xs + 4);
    float4 b2 = *(const float4*)(xs + 8);
    float4 b3 = *(const float4*)(xs + 12);
    bf16x8 t0, t1;
    t0[0] = (short)f2bf(b0.x); t0[1] = (short)f2bf(b0.y);
    t0[2] = (short)f2bf(b0.z); t0[3] = (short)f2bf(b0.w);
    t0[4] = (short)f2bf(b1.x); t0[5] = (short)f2bf(b1.y);
    t0[6] = (short)f2bf(b1.z); t0[7] = (short)f2bf(b1.w);
    t1[0] = (short)f2bf(b2.x); t1[1] = (short)f2bf(b2.y);
    t1[2] = (short)f2bf(b2.z); t1[3] = (short)f2bf(b2.w);
    t1[4] = (short)f2bf(b3.x); t1[5] = (short)f2bf(b3.y);
    t1[6] = (short)f2bf(b3.z); t1[7] = (short)f2bf(b3.w);
    *(bf16x8*)&Ash[3 + (c >> 1)][row][(c & 1) * 16] = t0;
    *(bf16x8*)&Ash[3 + (c >> 1)][row][(c & 1) * 16 + 8] = t1;
  }
  __syncthreads();

  // MFMA: 5 K-steps x 4 M-tiles x {f,s}
  f32x4 accf[4], accs[4];
#pragma unroll
  for (int mt = 0; mt < 4; ++mt) {
    accf[mt] = (f32x4){0.f, 0.f, 0.f, 0.f};
    accs[mt] = (f32x4){0.f, 0.f, 0.f, 0.f};
  }
#pragma unroll
  for (int ks = 0; ks < 5; ++ks) {
#pragma unroll
    for (int mt = 0; mt < 4; ++mt) {
      const bf16x8 a = *(const bf16x8*)&Ash[ks][mt * 16 + q][g * 8];
      accf[mt] =
          __builtin_amdgcn_mfma_f32_16x16x32_bf16(a, Bf[ks], accf[mt], 0, 0, 0);
      accs[mt] =
          __builtin_amdgcn_mfma_f32_16x16x32_bf16(a, Bs[ks], accs[mt], 0, 0, 0);
    }
  }

  // epilogue: lane covers edges e = mt*16 + g*4 + reg, single feat.
#pragma unroll
  for (int mt = 0; mt < 4; ++mt) {
    const int e0 = mt * 16 + g * 4;
    const unsigned rid4 = *(const unsigned*)&ridb[e0];
    const int4 d4 = *(const int4*)&dstl[e0];
    float m[4];
#pragma unroll
    for (int r = 0; r < 4; ++r) {
      float F = accf[mt][r] + bfv;
      float S = accs[mt][r] + bsv;
      float sig = __builtin_amdgcn_rcpf(1.0f + __expf(-F));
      float sp = fmaxf(S, 0.f) + __logf(1.0f + __expf(-fabsf(S)));
      m[r] = sig * sp;
    }
    const int r0 = rid4 & 255, r1 = (rid4 >> 8) & 255, r2 = (rid4 >> 16) & 255,
              r3 = rid4 >> 24;
    float a_ = m[0];
    int cur = r0, dc = d4.x;
    if (r1 == cur) a_ += m[1];
    else {
      if (dc < N) atomicAdd(&agg[(size_t)dc * 64 + feat], a_);
      cur = r1; dc = d4.y; a_ = m[1];
    }
    if (r2 == cur) a_ += m[2];
    else {
      if (dc < N) atomicAdd(&agg[(size_t)dc * 64 + feat], a_);
      cur = r2; dc = d4.z; a_ = m[2];
    }
    if (r3 == cur) a_ += m[3];
    else {
      if (dc < N) atomicAdd(&agg[(size_t)dc * 64 + feat], a_);
      cur = r3; dc = d4.w; a_ = m[3];
    }
    if (dc < N) atomicAdd(&agg[(size_t)dc * 64 + feat], a_);
  }
}

// ---------------- K3: per-feature reductions over agg and x ----------------
__global__ __launch_bounds__(256) void stats_kernel(
    const float* __restrict__ agg, const float* __restrict__ x,
    float* __restrict__ stats, int N) {
  const int f = threadIdx.x & 63;
  const int sub = threadIdx.x >> 6;
  float sa = 0, sa2 = 0, sx = 0, sx2 = 0, sax = 0;
  for (int r = blockIdx.x * 4 + sub; r < N; r += gridDim.x * 4) {
    float a = agg[(size_t)r * 64 + f];
    float xv = x[(size_t)r * 64 + f];
    sa += a; sa2 += a * a; sx += xv; sx2 += xv * xv; sax += a * xv;
  }
  __shared__ float lds[4][5][64];
  lds[sub][0][f] = sa; lds[sub][1][f] = sa2; lds[sub][2][f] = sx;
  lds[sub][3][f] = sx2; lds[sub][4][f] = sax;
  __syncthreads();
  if (sub == 0) {
#pragma unroll
    for (int i = 0; i < 5; ++i) {
      float v = lds[0][i][f] + lds[1][i][f] + lds[2][i][f] + lds[3][i][f];
      atomicAdd(&stats[i * 64 + f], v);
    }
  }
}

// ---------------- K5: (finalize folded in) BN+res+LN+softplus + pooling ------
__global__ __launch_bounds__(256) void node_finish(
    const float* __restrict__ stats, const float* __restrict__ bn_w,
    const float* __restrict__ bn_b, const float* __restrict__ agg,
    const float* __restrict__ x, const int* __restrict__ batch,
    const float* __restrict__ ln_w, const float* __restrict__ ln_b,
    float* __restrict__ add_pool, float* __restrict__ counts, int N,
    int chunk) {
  const int f = threadIdx.x & 63;
  const int sub = threadIdx.x >> 6;
  // per-wave redundant finalize (each wave holds all 64 f's)
  const float Nf = (float)N;
  const float invN = 1.0f / Nf;
  float Sa = stats[f], Sa2 = stats[64 + f], Sx = stats[128 + f],
        Sx2 = stats[192 + f], Sax = stats[256 + f];
  float mu = Sa * invN;
  float var = Sa2 * invN - mu * mu;
  const float alpha = bn_w[f] / sqrtf(var + EPSF);
  const float beta = bn_b[f] - mu * alpha;
  float Sh = alpha * Sa + Nf * beta + Sx;
  float Sh2 = alpha * alpha * Sa2 + Sx2 + Nf * beta * beta +
              2.f * alpha * Sax + 2.f * alpha * beta * Sa + 2.f * beta * Sx;
#pragma unroll
  for (int o = 32; o > 0; o >>= 1) {
    Sh += __shfl_xor(Sh, o);
    Sh2 += __shfl_xor(Sh2, o);
  }
  const float cnt = Nf * 64.0f;
  const float mean = Sh / cnt;
  const float msq = Sh2 / cnt - mean * mean;
  const float rden = 1.0f / (sqrtf(fmaxf(msq, 0.f)) + EPSF);
  const float lw = ln_w[f] * rden;
  const float lb = ln_b[f];

  const int r0 = blockIdx.x * chunk;
  const int r1 = min(N, r0 + chunk);
  float acc = 0.f, cacc = 0.f;
  int curg = -1;
  for (int r = r0 + sub; r < r1; r += 4) {
    int g = batch[r];
    if (g != curg) {
      if (curg >= 0) {
        atomicAdd(&add_pool[(size_t)curg * 64 + f], acc);
        if (f == 0) atomicAdd(&counts[curg], cacc);
      }
      curg = g; acc = 0.f; cacc = 0.f;
    }
    float h = fmaf(alpha, agg[(size_t)r * 64 + f], beta) + x[(size_t)r * 64 + f];
    float v = (h - mean) * lw + lb;
    float sp = fmaxf(v, 0.f) + __logf(1.0f + __expf(-fabsf(v)));
    acc += sp; cacc += 1.f;
  }
  if (curg >= 0) {
    atomicAdd(&add_pool[(size_t)curg * 64 + f], acc);
    if (f == 0) atomicAdd(&counts[curg], cacc);
  }
}

// ---------------- K6: graph head (vectorized) ----------------
__global__ __launch_bounds__(1024) void graph_out(
    const float* __restrict__ add_pool, const float* __restrict__ counts,
    const float* __restrict__ Wl, const float* __restrict__ bl,
    const float* __restrict__ w4, const float* __restrict__ b4,
    float* __restrict__ out, int G) {
  const int t = threadIdx.x;
  const int g = t >> 1, c = t & 1;
  float cnt = fmaxf(counts[g], 1.0f);
  float inv = 1.0f / cnt;
  const float4* ap4 = (const float4*)(add_pool + (size_t)g * 64);
  const float4* W4 = (const float4*)Wl;
  float v = bl[c];
#pragma unroll 4
  for (int k4 = 0; k4 < 16; ++k4) {
    float4 a4 = ap4[k4];
    float4 wa = W4[k4 * 2];          // rows 4k4,4k4+1 (mean part)
    float4 wb = W4[k4 * 2 + 1];      // rows 4k4+2,4k4+3
    float4 wc = W4[32 + k4 * 2];     // rows 64+4k4.. (add part)
    float4 wd = W4[32 + k4 * 2 + 1];
    float m0 = c ? wa.y : wa.x, m1 = c ? wa.w : wa.z;
    float m2 = c ? wb.y : wb.x, m3 = c ? wb.w : wb.z;
    float a0 = c ? wc.y : wc.x, a1 = c ? wc.w : wc.z;
    float a2 = c ? wd.y : wd.x, a3 = c ? wd.w : wd.z;
    v = fmaf(a4.x, fmaf(m0, inv, a0), v);
    v = fmaf(a4.y, fmaf(m1, inv, a1), v);
    v = fmaf(a4.z, fmaf(m2, inv, a2), v);
    v = fmaf(a4.w, fmaf(m3, inv, a3), v);
  }

  __shared__ float red[16];
  __shared__ float bc[2];
  float sum = v;
#pragma unroll
  for (int o = 32; o > 0; o >>= 1) sum += __shfl_down(sum, o);
  if ((t & 63) == 0) red[t >> 6] = sum;
  __syncthreads();
  if (t == 0) {
    float tot = 0;
#pragma unroll
    for (int i = 0; i < 16; ++i) tot += red[i];
    bc[0] = tot * (1.0f / 1024.0f);
  }
  __syncthreads();
  const float mean = bc[0];
  const float xc = v - mean;
  float sq = xc * xc;
  __syncthreads();
#pragma unroll
  for (int o = 32; o > 0; o >>= 1) sq += __shfl_down(sq, o);
  if ((t & 63) == 0) red[t >> 6] = sq;
  __syncthreads();
  if (t == 0) {
    float tot = 0;
#pragma unroll
    for (int i = 0; i < 16; ++i) tot += red[i];
    bc[1] = 1.0f / (sqrtf(tot * (1.0f / 1024.0f)) + EPSF);
  }
  __syncthreads();
  out[t] = xc * bc[1] * w4[c] + b4[c];
}

extern "C" void kernel_launch(void* const* d_in, const int* in_sizes, int n_in,
                              void* d_out, int out_size, void* d_ws,
                              size_t ws_size, hipStream_t stream) {
  const float* x = (const float*)d_in[0];
  const int* ei = (const int*)d_in[1];
  const float* eattr = (const float*)d_in[2];
  const int* batch = (const int*)d_in[3];
  const float* Wf = (const float*)d_in[4];
  const float* bf = (const float*)d_in[5];
  const float* Ws = (const float*)d_in[6];
  const float* bs = (const float*)d_in[7];
  const float* bn_w = (const float*)d_in[8];
  const float* bn_b = (const float*)d_in[9];
  const float* ln_w = (const float*)d_in[10];
  const float* ln_b = (const float*)d_in[11];
  const float* Wl = (const float*)d_in[12];
  const float* bl = (const float*)d_in[13];
  const float* w4 = (const float*)d_in[14];
  const float* b4 = (const float*)d_in[15];

  const int N = in_sizes[0] / 64;
  const int E = in_sizes[2] / 32;
  const int G = 512;
  const int NB = (N + 255) / 256;
  const int T = (E + 63) / 64;

  // Workspace layout (elements; every chunk multiple of 4 => 16B alignment).
  // Zero region is contiguous: [agg | stats | add_pool | counts | deg]
  float* ws = (float*)d_ws;
  float* agg = ws;                                   // N*64  [zeroed]
  float* stats = agg + (size_t)N * 64;               // 320   [zeroed]
  float* add_pool = stats + 320;                     // G*64  [zeroed]
  float* counts = add_pool + (size_t)G * 64;         // G     [zeroed]
  int* deg = (int*)(counts + G);                     // N     [zeroed]
  int* offsets = deg + N;                            // N+4
  int* cursor = offsets + N + 4;                     // N
  int* bsum = cursor + N;                            // 256
  int* bpre = bsum + 256;                            // 256
  unsigned short* Bfrag = (unsigned short*)(bpre + 256);  // 20480 ush
  int4* epair4 = (int4*)((int*)(bpre + 256) + 10240);     // E int4

  size_t zeroFloats = (size_t)N * 64 + 320 + (size_t)G * 64 + G + N;
  hipMemsetAsync(agg, 0, zeroFloats * sizeof(float), stream);

  bpack_kernel<<<5, 512, 0, stream>>>(Wf, Ws, Bfrag);
  hist_kernel<<<(E + 255) / 256, 256, 0, stream>>>(ei, deg, E);
  scan_a<<<NB, 256, 0, stream>>>(deg, bsum, N);
  scan_b<<<1, 256, 0, stream>>>(bsum, bpre, NB);
  scan_c<<<NB, 256, 0, stream>>>(deg, bpre, offsets, cursor, N);
  scatter_kernel<<<(E + 255) / 256, 256, 0, stream>>>(ei, cursor, epair4, E);
  edge_fused<<<T, 256, 0, stream>>>(epair4, eattr, x, Bfrag, bf, bs, agg, E, N);
  stats_kernel<<<512, 256, 0, stream>>>(agg, x, stats, N);
  const int chunk = (N + 511) / 512;
  node_finish<<<512, 256, 0, stream>>>(stats, bn_w, bn_b, agg, x, batch, ln_w,
                                       ln_b, add_pool, counts, N, chunk);
  graph_out<<<1, 1024, 0, stream>>>(add_pool, counts, Wl, bl, w4, b4,
                                    (float*)d_out, G);
}

// Round 8
// 328.681 us; speedup vs baseline: 1.0184x; 1.0184x over previous
//
#include <hip/hip_runtime.h>
#include <math.h>

#define EPSF 1e-5f

typedef short bf16x8 __attribute__((ext_vector_type(8)));
typedef float f32x4 __attribute__((ext_vector_type(4)));

static __device__ __forceinline__ unsigned short f2bf(float x) {
  unsigned u = __float_as_uint(x);
  unsigned r = (u + 0x7FFFu + ((u >> 16) & 1u)) >> 16;
  return (unsigned short)r;
}

union BU { uint4 u; bf16x8 v; };

// async global->LDS, 16B per lane; LDS dest = base + lane*16 (HW), global
// source address is per-lane.
static __device__ __forceinline__ void gload16(const void* g, void* l) {
  __builtin_amdgcn_global_load_lds(
      (const __attribute__((address_space(1))) unsigned int*)g,
      (__attribute__((address_space(3))) unsigned int*)l, 16, 0, 0);
}

// ---------------- Prep: x (fp32) -> bf16, 8 elems/thread ----------------
__global__ __launch_bounds__(256) void cvt_x(const float* __restrict__ x,
                                             unsigned short* __restrict__ xbf,
                                             int total8) {
  int i = blockIdx.x * 256 + threadIdx.x;
  if (i >= total8) return;
  float4 a = ((const float4*)x)[i * 2];
  float4 b = ((const float4*)x)[i * 2 + 1];
  unsigned short o[8];
  o[0] = f2bf(a.x); o[1] = f2bf(a.y); o[2] = f2bf(a.z); o[3] = f2bf(a.w);
  o[4] = f2bf(b.x); o[5] = f2bf(b.y); o[6] = f2bf(b.z); o[7] = f2bf(b.w);
  ((uint4*)xbf)[i] = *(uint4*)o;
}

// ---------------- Prep: pack [Wf|Ws] permuted rows into MFMA B-frag order ----
// Row space k=0..159: k<32 -> W[128+k] (eattr); 32..95 -> W[k-32] (x_dst);
// 96..159 -> W[k-32] (x_src). lane l holds B[k=(l>>4)*8+i][col=(t8&3)*16+(l&15)].
__global__ __launch_bounds__(512) void bpack_kernel(
    const float* __restrict__ Wf, const float* __restrict__ Ws,
    unsigned short* __restrict__ Bfrag) {
  const int ks = blockIdx.x;  // 0..4
  const int t8 = threadIdx.x >> 6, l = threadIdx.x & 63;
  const int q = l & 15, g = l >> 4;
  const float* W = (t8 < 4) ? Wf : Ws;
  const int col = (t8 & 3) * 16 + q;
  unsigned short out[8];
#pragma unroll
  for (int i = 0; i < 8; ++i) {
    int r = ks * 32 + g * 8 + i;
    int wr = (r < 32) ? (128 + r) : (r - 32);
    out[i] = f2bf(W[(size_t)wr * 64 + col]);
  }
  *(uint4*)&Bfrag[((size_t)(ks * 8 + t8) * 64 + l) * 8] = *(uint4*)out;
}

// ---------------- CSR build: histogram of dst ----------------
__global__ void hist_kernel(const int* __restrict__ ei, int* __restrict__ deg,
                            int E) {
  int i = blockIdx.x * blockDim.x + threadIdx.x;
  if (i < E) atomicAdd(&deg[ei[E + i]], 1);
}

// ---------------- CSR build: 3-phase parallel exclusive scan ----------------
__global__ __launch_bounds__(256) void scan_a(const int* __restrict__ deg,
                                              int* __restrict__ bsum, int N) {
  const int idx = blockIdx.x * 256 + threadIdx.x;
  int v = (idx < N) ? deg[idx] : 0;
#pragma unroll
  for (int o = 32; o > 0; o >>= 1) v += __shfl_down(v, o);
  __shared__ int ws4[4];
  if ((threadIdx.x & 63) == 0) ws4[threadIdx.x >> 6] = v;
  __syncthreads();
  if (threadIdx.x == 0) bsum[blockIdx.x] = ws4[0] + ws4[1] + ws4[2] + ws4[3];
}

__global__ __launch_bounds__(256) void scan_b(const int* __restrict__ bsum,
                                              int* __restrict__ bpre, int NB) {
  const int t = threadIdx.x;
  const int lane = t & 63, w = t >> 6;
  int v = (t < NB) ? bsum[t] : 0;
  int sc = v;
#pragma unroll
  for (int o = 1; o < 64; o <<= 1) {
    int u = __shfl_up(sc, o);
    if (lane >= o) sc += u;
  }
  __shared__ int wsum[4];
  if (lane == 63) wsum[w] = sc;
  __syncthreads();
  int add = 0;
#pragma unroll
  for (int k = 0; k < 4; ++k) add += (k < w) ? wsum[k] : 0;
  bpre[t] = (sc - v) + add;
}

__global__ __launch_bounds__(256) void scan_c(const int* __restrict__ deg,
                                              const int* __restrict__ bpre,
                                              int* __restrict__ offsets,
                                              int* __restrict__ cursor, int N) {
  const int t = threadIdx.x;
  const int lane = t & 63, w = t >> 6;
  const int idx = blockIdx.x * 256 + t;
  int d = (idx < N) ? deg[idx] : 0;
  int sc = d;
#pragma unroll
  for (int o = 1; o < 64; o <<= 1) {
    int u = __shfl_up(sc, o);
    if (lane >= o) sc += u;
  }
  __shared__ int wsum[4];
  if (lane == 63) wsum[w] = sc;
  __syncthreads();
  int add = bpre[blockIdx.x];
#pragma unroll
  for (int k = 0; k < 4; ++k) add += (k < w) ? wsum[k] : 0;
  const int off = add + (sc - d);
  if (idx < N) {
    offsets[idx] = off;
    cursor[idx] = off;
    if (idx == N - 1) offsets[N] = off + d;
  }
}

// ---------------- CSR build: scatter (eattr_idx, src, dst) -----------------
__global__ void scatter_kernel(const int* __restrict__ ei,
                               int* __restrict__ cursor,
                               int4* __restrict__ epair4, int E) {
  int i = blockIdx.x * blockDim.x + threadIdx.x;
  if (i < E) {
    int dst = ei[E + i];
    int pos = atomicAdd(&cursor[dst], 1);
    epair4[pos] = make_int4(i, ei[i], dst, 0);
  }
}

// ---------------- K2: fused edge kernel. One block = 64-edge tile ------------
// A(64x160 bf16) = [eattr | x_dst | x_src] in LDS [5][64][32] (64B rows,
// conflict-free). x staged via global_load_lds from pre-converted bf16;
// eattr staged fp32->bf16 (8 elems/thread). B(160x128) in VGPRs.
// 40 MFMA 16x16x32 per wave; epilogue: bias + sigmoid*softplus +
// run-compressed atomicAdd into agg.
__global__ __launch_bounds__(256) void edge_fused(
    const int4* __restrict__ epair4, const float* __restrict__ eattr,
    const unsigned short* __restrict__ xbf,
    const unsigned short* __restrict__ Bfrag, const float* __restrict__ bfv_,
    const float* __restrict__ bsv_, float* __restrict__ agg, int E, int N) {
  __shared__ __align__(16) unsigned short Ash[5][64][32];  // 20 KB
  __shared__ __align__(16) int srcl[64];
  __shared__ __align__(16) int dstl[64];
  __shared__ __align__(16) int eidx[64];
  __shared__ __align__(4) unsigned char ridb[64];

  const int t = threadIdx.x, lane = t & 63, w = t >> 6;
  const int q = lane & 15, g = lane >> 4;
  const int base = blockIdx.x * 64;

  // B fragments: 10 x 16B loads per lane (L1/L2-hot), wave-uniform tiles
  bf16x8 Bf[5], Bs[5];
#pragma unroll
  for (int ks = 0; ks < 5; ++ks) {
    BU u1, u2;
    u1.u = ((const uint4*)Bfrag)[(size_t)((ks * 8 + w) * 64 + lane)];
    u2.u = ((const uint4*)Bfrag)[(size_t)((ks * 8 + w + 4) * 64 + lane)];
    Bf[ks] = u1.v;
    Bs[ks] = u2.v;
  }
  const int feat = w * 16 + q;
  const float bfv = bfv_[feat];
  const float bsv = bsv_[feat];

  // wave 0: edge meta + dst run-id scan (dst-sorted CSR order)
  if (w == 0) {
    const int eg = base + lane;
    int4 p = make_int4(0, 0, 0x7FFFFFFF, 0);
    if (eg < E) p = epair4[eg];
    eidx[lane] = p.x;
    srcl[lane] = p.y;
    dstl[lane] = p.z;
    int d = p.z;
    int dprev = __shfl_up(d, 1);
    int flag = (lane == 0 || d != dprev) ? 1 : 0;
    int sc = flag;
#pragma unroll
    for (int o = 1; o < 64; o <<= 1) {
      int u = __shfl_up(sc, o);
      if (lane >= o) sc += u;
    }
    ridb[lane] = (unsigned char)(sc - 1);
  }
  __syncthreads();

  // ---- stage x_dst (steps 1-2) and x_src (steps 3-4) via global_load_lds.
  // Region layout is linear: chunk k (1KB) = step 1+(k>>2), rows 16*(k&3)..+15.
  // Wave w issues chunks {w, w+4} for each region: lane offset = lane*16.
  char* AshB = (char*)&Ash[0][0][0];
#pragma unroll
  for (int c2 = 0; c2 < 2; ++c2) {
    const int k = w + c2 * 4;
    const int row = 16 * (k & 3) + (lane >> 2);
    const int half = (k >> 2) * 32 + (lane & 3) * 8;  // bf16 col offset in x row
    int d = dstl[row];
    if ((unsigned)d >= (unsigned)N) d = 0;
    gload16(xbf + (size_t)d * 64 + half, AshB + 4096 + (size_t)k * 1024);
    const int s = srcl[row];
    gload16(xbf + (size_t)s * 64 + half, AshB + 12288 + (size_t)k * 1024);
  }

  // ---- stage eattr (step 0): fp32 gather -> bf16, 8 elems/thread ----
  {
    const int row = t >> 2, c = t & 3;
    const float* er = eattr + (size_t)eidx[row] * 32 + c * 8;
    float4 v0 = *(const float4*)er;
    float4 v1 = *(const float4*)(er + 4);
    bf16x8 sv;
    sv[0] = (short)f2bf(v0.x); sv[1] = (short)f2bf(v0.y);
    sv[2] = (short)f2bf(v0.z); sv[3] = (short)f2bf(v0.w);
    sv[4] = (short)f2bf(v1.x); sv[5] = (short)f2bf(v1.y);
    sv[6] = (short)f2bf(v1.z); sv[7] = (short)f2bf(v1.w);
    *(bf16x8*)&Ash[0][row][c * 8] = sv;
  }
  __syncthreads();  // drains vmcnt (global_load_lds) + lgkm (ds_write)

  // ---- MFMA: 5 K-steps x 4 M-tiles x {f,s} ----
  f32x4 accf[4], accs[4];
#pragma unroll
  for (int mt = 0; mt < 4; ++mt) {
    accf[mt] = (f32x4){0.f, 0.f, 0.f, 0.f};
    accs[mt] = (f32x4){0.f, 0.f, 0.f, 0.f};
  }
#pragma unroll
  for (int ks = 0; ks < 5; ++ks) {
#pragma unroll
    for (int mt = 0; mt < 4; ++mt) {
      const bf16x8 a = *(const bf16x8*)&Ash[ks][mt * 16 + q][g * 8];
      accf[mt] =
          __builtin_amdgcn_mfma_f32_16x16x32_bf16(a, Bf[ks], accf[mt], 0, 0, 0);
      accs[mt] =
          __builtin_amdgcn_mfma_f32_16x16x32_bf16(a, Bs[ks], accs[mt], 0, 0, 0);
    }
  }

  // ---- epilogue: lane covers edges e = mt*16 + g*4 + reg, one feat ----
#pragma unroll
  for (int mt = 0; mt < 4; ++mt) {
    const int e0 = mt * 16 + g * 4;
    const unsigned rid4 = *(const unsigned*)&ridb[e0];
    const int4 d4 = *(const int4*)&dstl[e0];
    float m[4];
#pragma unroll
    for (int r = 0; r < 4; ++r) {
      float F = accf[mt][r] + bfv;
      float S = accs[mt][r] + bsv;
      float sig = __builtin_amdgcn_rcpf(1.0f + __expf(-F));
      float sp = fmaxf(S, 0.f) + __logf(1.0f + __expf(-fabsf(S)));
      m[r] = sig * sp;
    }
    const int r0 = rid4 & 255, r1 = (rid4 >> 8) & 255, r2 = (rid4 >> 16) & 255,
              r3 = rid4 >> 24;
    float a_ = m[0];
    int cur = r0, dc = d4.x;
    if (r1 == cur) a_ += m[1];
    else {
      if (dc < N) atomicAdd(&agg[(size_t)dc * 64 + feat], a_);
      cur = r1; dc = d4.y; a_ = m[1];
    }
    if (r2 == cur) a_ += m[2];
    else {
      if (dc < N) atomicAdd(&agg[(size_t)dc * 64 + feat], a_);
      cur = r2; dc = d4.z; a_ = m[2];
    }
    if (r3 == cur) a_ += m[3];
    else {
      if (dc < N) atomicAdd(&agg[(size_t)dc * 64 + feat], a_);
      cur = r3; dc = d4.w; a_ = m[3];
    }
    if (dc < N) atomicAdd(&agg[(size_t)dc * 64 + feat], a_);
  }
}

// ---------------- K3: per-feature reductions over agg and x ----------------
__global__ __launch_bounds__(256) void stats_kernel(
    const float* __restrict__ agg, const float* __restrict__ x,
    float* __restrict__ stats, int N) {
  const int f = threadIdx.x & 63;
  const int sub = threadIdx.x >> 6;
  float sa = 0, sa2 = 0, sx = 0, sx2 = 0, sax = 0;
  for (int r = blockIdx.x * 4 + sub; r < N; r += gridDim.x * 4) {
    float a = agg[(size_t)r * 64 + f];
    float xv = x[(size_t)r * 64 + f];
    sa += a; sa2 += a * a; sx += xv; sx2 += xv * xv; sax += a * xv;
  }
  __shared__ float lds[4][5][64];
  lds[sub][0][f] = sa; lds[sub][1][f] = sa2; lds[sub][2][f] = sx;
  lds[sub][3][f] = sx2; lds[sub][4][f] = sax;
  __syncthreads();
  if (sub == 0) {
#pragma unroll
    for (int i = 0; i < 5; ++i) {
      float v = lds[0][i][f] + lds[1][i][f] + lds[2][i][f] + lds[3][i][f];
      atomicAdd(&stats[i * 64 + f], v);
    }
  }
}

// ---------------- K5: finalize + BN+res+LN+softplus + pooling ----------------
__global__ __launch_bounds__(256) void node_finish(
    const float* __restrict__ stats, const float* __restrict__ bn_w,
    const float* __restrict__ bn_b, const float* __restrict__ agg,
    const float* __restrict__ x, const int* __restrict__ batch,
    const float* __restrict__ ln_w, const float* __restrict__ ln_b,
    float* __restrict__ add_pool, float* __restrict__ counts, int N,
    int chunk) {
  const int f = threadIdx.x & 63;
  const int sub = threadIdx.x >> 6;
  const float Nf = (float)N;
  const float invN = 1.0f / Nf;
  float Sa = stats[f], Sa2 = stats[64 + f], Sx = stats[128 + f],
        Sx2 = stats[192 + f], Sax = stats[256 + f];
  float mu = Sa * invN;
  float var = Sa2 * invN - mu * mu;
  const float alpha = bn_w[f] / sqrtf(var + EPSF);
  const float beta = bn_b[f] - mu * alpha;
  float Sh = alpha * Sa + Nf * beta + Sx;
  float Sh2 = alpha * alpha * Sa2 + Sx2 + Nf * beta * beta +
              2.f * alpha * Sax + 2.f * alpha * beta * Sa + 2.f * beta * Sx;
#pragma unroll
  for (int o = 32; o > 0; o >>= 1) {
    Sh += __shfl_xor(Sh, o);
    Sh2 += __shfl_xor(Sh2, o);
  }
  const float cnt = Nf * 64.0f;
  const float mean = Sh / cnt;
  const float msq = Sh2 / cnt - mean * mean;
  const float rden = 1.0f / (sqrtf(fmaxf(msq, 0.f)) + EPSF);
  const float lw = ln_w[f] * rden;
  const float lb = ln_b[f];

  const int r0 = blockIdx.x * chunk;
  const int r1 = min(N, r0 + chunk);
  float acc = 0.f, cacc = 0.f;
  int curg = -1;
  for (int r = r0 + sub; r < r1; r += 4) {
    int g = batch[r];
    if (g != curg) {
      if (curg >= 0) {
        atomicAdd(&add_pool[(size_t)curg * 64 + f], acc);
        if (f == 0) atomicAdd(&counts[curg], cacc);
      }
      curg = g; acc = 0.f; cacc = 0.f;
    }
    float h = fmaf(alpha, agg[(size_t)r * 64 + f], beta) + x[(size_t)r * 64 + f];
    float v = (h - mean) * lw + lb;
    float sp = fmaxf(v, 0.f) + __logf(1.0f + __expf(-fabsf(v)));
    acc += sp; cacc += 1.f;
  }
  if (curg >= 0) {
    atomicAdd(&add_pool[(size_t)curg * 64 + f], acc);
    if (f == 0) atomicAdd(&counts[curg], cacc);
  }
}

// ---------------- K6: graph head (vectorized) ----------------
__global__ __launch_bounds__(1024) void graph_out(
    const float* __restrict__ add_pool, const float* __restrict__ counts,
    const float* __restrict__ Wl, const float* __restrict__ bl,
    const float* __restrict__ w4, const float* __restrict__ b4,
    float* __restrict__ out, int G) {
  const int t = threadIdx.x;
  const int g = t >> 1, c = t & 1;
  float cnt = fmaxf(counts[g], 1.0f);
  float inv = 1.0f / cnt;
  const float4* ap4 = (const float4*)(add_pool + (size_t)g * 64);
  const float4* W4 = (const float4*)Wl;
  float v = bl[c];
#pragma unroll 4
  for (int k4 = 0; k4 < 16; ++k4) {
    float4 a4 = ap4[k4];
    float4 wa = W4[k4 * 2];
    float4 wb = W4[k4 * 2 + 1];
    float4 wc = W4[32 + k4 * 2];
    float4 wd = W4[32 + k4 * 2 + 1];
    float m0 = c ? wa.y : wa.x, m1 = c ? wa.w : wa.z;
    float m2 = c ? wb.y : wb.x, m3 = c ? wb.w : wb.z;
    float a0 = c ? wc.y : wc.x, a1 = c ? wc.w : wc.z;
    float a2 = c ? wd.y : wd.x, a3 = c ? wd.w : wd.z;
    v = fmaf(a4.x, fmaf(m0, inv, a0), v);
    v = fmaf(a4.y, fmaf(m1, inv, a1), v);
    v = fmaf(a4.z, fmaf(m2, inv, a2), v);
    v = fmaf(a4.w, fmaf(m3, inv, a3), v);
  }

  __shared__ float red[16];
  __shared__ float bc[2];
  float sum = v;
#pragma unroll
  for (int o = 32; o > 0; o >>= 1) sum += __shfl_down(sum, o);
  if ((t & 63) == 0) red[t >> 6] = sum;
  __syncthreads();
  if (t == 0) {
    float tot = 0;
#pragma unroll
    for (int i = 0; i < 16; ++i) tot += red[i];
    bc[0] = tot * (1.0f / 1024.0f);
  }
  __syncthreads();
  const float mean = bc[0];
  const float xc = v - mean;
  float sq = xc * xc;
  __syncthreads();
#pragma unroll
  for (int o = 32; o > 0; o >>= 1) sq += __shfl_down(sq, o);
  if ((t & 63) == 0) red[t >> 6] = sq;
  __syncthreads();
  if (t == 0) {
    float tot = 0;
#pragma unroll
    for (int i = 0; i < 16; ++i) tot += red[i];
    bc[1] = 1.0f / (sqrtf(tot * (1.0f / 1024.0f)) + EPSF);
  }
  __syncthreads();
  out[t] = xc * bc[1] * w4[c] + b4[c];
}

extern "C" void kernel_launch(void* const* d_in, const int* in_sizes, int n_in,
                              void* d_out, int out_size, void* d_ws,
                              size_t ws_size, hipStream_t stream) {
  const float* x = (const float*)d_in[0];
  const int* ei = (const int*)d_in[1];
  const float* eattr = (const float*)d_in[2];
  const int* batch = (const int*)d_in[3];
  const float* Wf = (const float*)d_in[4];
  const float* bf = (const float*)d_in[5];
  const float* Ws = (const float*)d_in[6];
  const float* bs = (const float*)d_in[7];
  const float* bn_w = (const float*)d_in[8];
  const float* bn_b = (const float*)d_in[9];
  const float* ln_w = (const float*)d_in[10];
  const float* ln_b = (const float*)d_in[11];
  const float* Wl = (const float*)d_in[12];
  const float* bl = (const float*)d_in[13];
  const float* w4 = (const float*)d_in[14];
  const float* b4 = (const float*)d_in[15];

  const int N = in_sizes[0] / 64;
  const int E = in_sizes[2] / 32;
  const int G = 512;
  const int NB = (N + 255) / 256;
  const int T = (E + 63) / 64;

  // Workspace layout (elements; each chunk multiple of 4 => 16B alignment).
  // Zero region contiguous: [agg | stats | add_pool | counts | deg]
  float* ws = (float*)d_ws;
  float* agg = ws;                                   // N*64  [zeroed]
  float* stats = agg + (size_t)N * 64;               // 320   [zeroed]
  float* add_pool = stats + 320;                     // G*64  [zeroed]
  float* counts = add_pool + (size_t)G * 64;         // G     [zeroed]
  int* deg = (int*)(counts + G);                     // N     [zeroed]
  int* offsets = deg + N;                            // N+4
  int* cursor = offsets + N + 4;                     // N
  int* bsum = cursor + N;                            // 256
  int* bpre = bsum + 256;                            // 256
  unsigned short* Bfrag = (unsigned short*)(bpre + 256);   // 20480 ush
  unsigned short* xbf = Bfrag + 20480;                     // N*64 ush
  int4* epair4 = (int4*)(xbf + (size_t)N * 64);            // E int4

  size_t zeroFloats = (size_t)N * 64 + 320 + (size_t)G * 64 + G + N;
  hipMemsetAsync(agg, 0, zeroFloats * sizeof(float), stream);

  cvt_x<<<(N * 64 / 8 + 255) / 256, 256, 0, stream>>>(x, xbf, N * 64 / 8);
  bpack_kernel<<<5, 512, 0, stream>>>(Wf, Ws, Bfrag);
  hist_kernel<<<(E + 255) / 256, 256, 0, stream>>>(ei, deg, E);
  scan_a<<<NB, 256, 0, stream>>>(deg, bsum, N);
  scan_b<<<1, 256, 0, stream>>>(bsum, bpre, NB);
  scan_c<<<NB, 256, 0, stream>>>(deg, bpre, offsets, cursor, N);
  scatter_kernel<<<(E + 255) / 256, 256, 0, stream>>>(ei, cursor, epair4, E);
  edge_fused<<<T, 256, 0, stream>>>(epair4, eattr, xbf, Bfrag, bf, bs, agg, E,
                                    N);
  stats_kernel<<<512, 256, 0, stream>>>(agg, x, stats, N);
  const int chunk = (N + 511) / 512;
  node_finish<<<512, 256, 0, stream>>>(stats, bn_w, bn_b, agg, x, batch, ln_w,
                                       ln_b, add_pool, counts, N, chunk);
  graph_out<<<1, 1024, 0, stream>>>(add_pool, counts, Wl, bl, w4, b4,
                                    (float*)d_out, G);
}